// Round 15
// baseline (111.556 us; speedup 1.0000x reference)
//
#include <hip/hip_runtime.h>

typedef __bf16 bf16_t;
typedef bf16_t bf16x8 __attribute__((ext_vector_type(8)));
typedef bf16_t bf16x4 __attribute__((ext_vector_type(4)));
typedef float f32x4 __attribute__((ext_vector_type(4)));

#define SEQLEN 2048
#define EMB 1024
#define NHEADS 16
#define N3 3072
#define NBATCH 2
#define NEG_INF (-__builtin_inff())
#define SC2 0.18033688011112042f   // 0.125 * log2(e): softmax in exp2 domain

#define VMC8() do { asm volatile("s_waitcnt vmcnt(8)" ::: "memory"); \
                    __builtin_amdgcn_sched_barrier(0); } while (0)
#define VMC0() do { asm volatile("s_waitcnt vmcnt(0)" ::: "memory"); \
                    __builtin_amdgcn_sched_barrier(0); } while (0)

// async global->LDS, 16B per lane. LDS base must be wave-uniform.
__device__ __forceinline__ void async16(bf16_t* lds, const bf16_t* g) {
    __builtin_amdgcn_global_load_lds(
        (const __attribute__((address_space(1))) void*)g,
        (__attribute__((address_space(3))) void*)lds, 16, 0, 0);
}

// ---------------------------------------------------------------------------
// prep: fused X fp32->bf16 convert (blocks 0..2047) + weight transpose/convert
// (blocks 2048..3071; W_qkv Q-cols pre-scaled by SC2).
// ---------------------------------------------------------------------------
__global__ __launch_bounds__(256) void prep_kernel(
    const float* __restrict__ X, const float* __restrict__ Wqkv,
    const float* __restrict__ Wout, bf16_t* __restrict__ Xb,
    bf16_t* __restrict__ Wqkv_t, bf16_t* __restrict__ Wout_t)
{
    __shared__ float tile[64][65];
    const int id = blockIdx.x;
    const int t = threadIdx.x;
    if (id < 2048) {
        const int i = (id * 256 + t) * 8;
        float4 a = *(const float4*)&X[i];
        float4 b = *(const float4*)&X[i + 4];
        bf16_t v[8];
        v[0] = (bf16_t)a.x; v[1] = (bf16_t)a.y; v[2] = (bf16_t)a.z; v[3] = (bf16_t)a.w;
        v[4] = (bf16_t)b.x; v[5] = (bf16_t)b.y; v[6] = (bf16_t)b.z; v[7] = (bf16_t)b.w;
        *(float4*)&Xb[i] = *(float4*)&v[0];
        return;
    }
    const int wid2 = id - 2048;
    int bx = wid2 & 63;
    const int k0 = (wid2 >> 6) << 6;
    const float* W; bf16_t* Wt; int N; float s;
    if (bx < 48) { W = Wqkv; Wt = Wqkv_t; N = N3;  s = (bx * 64 < EMB) ? SC2 : 1.0f; }
    else         { bx -= 48; W = Wout; Wt = Wout_t; N = EMB; s = 1.0f; }
    const int n0 = bx * 64;
    const int nl = t & 63, k4 = t >> 6;
#pragma unroll
    for (int i = 0; i < 16; ++i) {
        int kk = k4 + i * 4;
        tile[kk][nl] = W[(size_t)(k0 + kk) * N + n0 + nl];
    }
    __syncthreads();
    const int kl = t & 63, n4 = t >> 6;
#pragma unroll
    for (int i = 0; i < 16; ++i) {
        int nn = n4 + i * 4;
        Wt[(size_t)(n0 + nn) * EMB + k0 + kl] = (bf16_t)(tile[kl][nn] * s);
    }
}

// ---------------------------------------------------------------------------
// GEMM 128x128, BK=64, T2-swizzled, NOW double-buffered with counted-vmcnt
// prefetch (T3/T4 minimal): tile t+2 staged while computing t; vmcnt(8)
// keeps one tile's 8 global_load_lds in flight across barriers (never
// drains to 0 in steady state). 2 raw s_barriers per step.
// V_SPLIT epilogue stores V^T quad-permuted (sigma, r11-verified).
// ---------------------------------------------------------------------------
template<bool OUT_BF16, bool V_SPLIT>
__global__ __launch_bounds__(256) void gemm_bt_kernel(
    const bf16_t* __restrict__ A, const bf16_t* __restrict__ Bt,
    const float* __restrict__ bias, void* __restrict__ Cp,
    bf16_t* __restrict__ vt, int scale_q,
    int Mdim, int Ndim, int Kdim)
{
    __shared__ bf16_t As[2][128 * 64];   // 32 KB
    __shared__ bf16_t Bs[2][128 * 64];   // 32 KB
    const int nb = Ndim >> 7;
    const int cpx = gridDim.x >> 3;
    const int bid = (blockIdx.x & 7) * cpx + (blockIdx.x >> 3);
    const int bx = bid % nb, by = bid / nb;
    const int r0 = by << 7, c0 = bx << 7;
    const int t = threadIdx.x, lane = t & 63;
    const int wid = t >> 6;
    const int wm = wid >> 1, wn = wid & 1;
    const int lr = lane & 15, lg = lane >> 4;

    const int glrow = wid * 32 + (lane >> 3);
    const int gsw = ((lane & 7) ^ (lane >> 3)) << 3;     // elems
    const bf16_t* gA = &A[(size_t)(r0 + glrow) * Kdim + gsw];
    const bf16_t* gB = &Bt[(size_t)(c0 + glrow) * Kdim + gsw];
    const size_t row8 = (size_t)8 * Kdim;

    const int fragb0 = (lr * 128 + lg * 16) ^ ((lr & 7) << 4);
    const int fragb1 = (lr * 128 + 64 + lg * 16) ^ ((lr & 7) << 4);

    auto stage = [&](int buf, int kt) {
        const bf16_t* a = gA + kt * 64;
        const bf16_t* b = gB + kt * 64;
        bf16_t* dA = &As[buf][wid * 2048];
        bf16_t* dB = &Bs[buf][wid * 2048];
        async16(dA,        a);
        async16(dA + 512,  a + row8);
        async16(dA + 1024, a + 2 * row8);
        async16(dA + 1536, a + 3 * row8);
        async16(dB,        b);
        async16(dB + 512,  b + row8);
        async16(dB + 1024, b + 2 * row8);
        async16(dB + 1536, b + 3 * row8);
    };

    f32x4 acc[4][4] = {};
    const int KT = Kdim >> 6;

    // prologue: stage t0 and t1
    stage(0, 0);
    if (KT > 1) { stage(1, 1); VMC8(); } else { VMC0(); }
    __builtin_amdgcn_s_barrier();

    for (int kt = 0; kt < KT; ++kt) {
        const int cur = kt & 1;
        const char* Ab = (const char*)&As[cur][0] + wm * 8192;
        const char* Bb = (const char*)&Bs[cur][0] + wn * 8192;
        bf16x8 af[4], bfm[4];
#pragma unroll
        for (int m = 0; m < 4; ++m)
            af[m] = *(const bf16x8*)(Ab + m * 2048 + fragb0);
#pragma unroll
        for (int n = 0; n < 4; ++n)
            bfm[n] = *(const bf16x8*)(Bb + n * 2048 + fragb0);
#pragma unroll
        for (int m = 0; m < 4; ++m)
#pragma unroll
            for (int n = 0; n < 4; ++n)
                acc[m][n] = __builtin_amdgcn_mfma_f32_16x16x32_bf16(
                    af[m], bfm[n], acc[m][n], 0, 0, 0);
#pragma unroll
        for (int m = 0; m < 4; ++m)
            af[m] = *(const bf16x8*)(Ab + m * 2048 + fragb1);
#pragma unroll
        for (int n = 0; n < 4; ++n)
            bfm[n] = *(const bf16x8*)(Bb + n * 2048 + fragb1);
#pragma unroll
        for (int m = 0; m < 4; ++m)
#pragma unroll
            for (int n = 0; n < 4; ++n)
                acc[m][n] = __builtin_amdgcn_mfma_f32_16x16x32_bf16(
                    af[m], bfm[n], acc[m][n], 0, 0, 0);

        __builtin_amdgcn_s_barrier();          // all reads of cur done
        if (kt + 2 < KT) { stage(cur, kt + 2); VMC8(); }  // t+1 landed
        else if (kt + 1 < KT) { VMC0(); }
        __builtin_amdgcn_s_barrier();          // next tile visible to all
    }

    const bool vmode = V_SPLIT && (c0 >= 2 * EMB);
    const int lgp = ((lg & 1) << 1) | (lg >> 1);   // sigma: 0->0,1->2,2->1,3->3
#pragma unroll
    for (int m = 0; m < 4; ++m) {
#pragma unroll
        for (int n = 0; n < 4; ++n) {
            const int col = c0 + wn * 64 + n * 16 + lr;
            float bval = bias[col];
            if (scale_q && col < EMB) bval *= SC2;
            if (vmode) {
                const int h = (col - 2 * EMB) >> 6, dd = col & 63;
                const int bb = r0 >> 11;
                const int sbase = (r0 & (SEQLEN - 1)) + wm * 64 + m * 16 + lgp * 4;
                bf16x4 pk;
#pragma unroll
                for (int j = 0; j < 4; ++j) pk[j] = (bf16_t)(acc[m][n][j] + bval);
                *(bf16x4*)&vt[(size_t)((bb * 16 + h) * 64 + dd) * SEQLEN + sbase] = pk;
            } else {
#pragma unroll
                for (int j = 0; j < 4; ++j) {
                    const int row = r0 + wm * 64 + m * 16 + lg * 4 + j;
                    const float v = acc[m][n][j] + bval;
                    if (OUT_BF16)
                        ((bf16_t*)Cp)[(size_t)row * Ndim + col] = (bf16_t)v;
                    else
                        ((float*)Cp)[(size_t)row * Ndim + col] = v;
                }
            }
        }
    }
}

// ---------------------------------------------------------------------------
// Causal flash attention v11 = v10 (8-wave, QBLK=128, KVBLK=128) with the
// V^T tile restructured as TWO [64 d][64 s] half-tiles (128-B rows, the
// r13-proven conflict-free 3-bit swizzle) instead of one 256-B-row tile.
// PV reads use the same kfb0/kfb1 bases as K (+8192 for s-half 1).
// ---------------------------------------------------------------------------
__global__ __launch_bounds__(512, 4) void attn_kernel(
    const bf16_t* __restrict__ qkv, const bf16_t* __restrict__ vt,
    bf16_t* __restrict__ attn_out)
{
    __shared__ bf16_t Kl[2][8192];    // [128 k][64 d], 128-B rows
    __shared__ bf16_t Vl[2][8192];    // [2 s-half][64 d][64 s], 128-B rows
    const int d = blockIdx.x;
    const int r = d >> 8;
    const int u = (d >> 5) & 7;
    const int bh = d & 31;
    const int qt = r ? u : (15 - u);      // long blocks first
    const int b = bh >> 4, h = bh & 15;
    const int q0 = qt << 7;
    const int t = threadIdx.x, lane = t & 63, wid = t >> 6;
    const int lr = lane & 15, lg = lane >> 4;

    // fragment bases, 128-B rows: XOR after all sub-bit-7 adds
    const int kfb0 = (lr * 128 + lg * 16) ^ ((lr & 7) << 4);
    const int kfb1 = (lr * 128 + 64 + lg * 16) ^ ((lr & 7) << 4);

    // staging: K 8 thr/row (rows t>>3, +64 via +8192); V half-tiles:
    // row srv (+32 via +4096), s-half from scv>>6.
    const int srk = t >> 3, sck = (t & 7) << 3;
    const int srv = t >> 4, scv = (t & 15) << 3;
    const int stbK = (srk * 128 + sck * 2) ^ ((srk & 7) << 4);
    const int stbV = (((srv * 128 + (scv & 63) * 2) ^ ((srv & 7) << 4)))
                     + ((scv >> 6) << 13);

    const bf16_t* kp = &qkv[(size_t)(b * SEQLEN + srk) * N3 + EMB + h * 64 + sck];
    const bf16_t* vp = &vt[(size_t)(bh * 64 + srv) * SEQLEN + scv];
    const size_t kstep  = (size_t)128 * N3;
    const size_t krow64 = (size_t)64 * N3;
    const size_t vrow32 = (size_t)32 * SEQLEN;

    const int qb = q0 + wid * 16;
    const int qg = qb + lr;
    bf16x8 qa0, qa1;
    {
        const bf16_t* qp = &qkv[(size_t)(b * SEQLEN + qg) * N3 + h * 64];
        qa0 = *(const bf16x8*)&qp[lg * 8];
        qa1 = *(const bf16x8*)&qp[32 + lg * 8];
    }
    bf16x8 ones;
#pragma unroll
    for (int i = 0; i < 8; ++i) ones[i] = (bf16_t)1.0f;

    f32x4 o[4] = {};
    f32x4 ol = {};
    float m_run = NEG_INF;

    auto stage = [&](int buf, float4 k0, float4 k1, float4 v0, float4 v1) {
        char* K = (char*)Kl[buf]; char* V = (char*)Vl[buf];
        *(float4*)(K + stbK) = k0; *(float4*)(K + stbK + 8192) = k1;
        *(float4*)(V + stbV) = v0; *(float4*)(V + stbV + 4096) = v1;
    };

    {   // prologue
        float4 k0 = *(const float4*)kp, k1 = *(const float4*)(kp + krow64);
        float4 v0 = *(const float4*)vp, v1 = *(const float4*)(vp + vrow32);
        stage(0, k0, k1, v0, v1);
    }
    __syncthreads();
    int cur = 0;
    for (int kt = 0; kt <= qt; ++kt) {
        float4 nk0, nk1, nv0, nv1;
        const bool more = (kt < qt);
        if (more) {          // T14 issue-early
            kp += kstep; vp += 128;
            nk0 = *(const float4*)kp; nk1 = *(const float4*)(kp + krow64);
            nv0 = *(const float4*)vp; nv1 = *(const float4*)(vp + vrow32);
        }

        const char* Kc = (const char*)Kl[cur];
        const char* Vc = (const char*)Vl[cur];
        const int kbase = kt << 7;

        f32x4 sc[8] = {};
        __builtin_amdgcn_s_setprio(1);
#pragma unroll
        for (int n = 0; n < 8; ++n) {
            bf16x8 kb0 = *(const bf16x8*)(Kc + (kfb0 + n * 2048));
            bf16x8 kb1 = *(const bf16x8*)(Kc + (kfb1 + n * 2048));
            sc[n] = __builtin_amdgcn_mfma_f32_16x16x32_bf16(kb0, qa0, sc[n], 0, 0, 0);
            sc[n] = __builtin_amdgcn_mfma_f32_16x16x32_bf16(kb1, qa1, sc[n], 0, 0, 0);
        }
        __builtin_amdgcn_s_setprio(0);

        if (kt == qt) {
#pragma unroll
            for (int n = 0; n < 8; ++n)
#pragma unroll
                for (int j = 0; j < 4; ++j) {
                    const int kg = kbase + n * 16 + lg * 4 + j;
                    sc[n][j] = (kg <= qg) ? sc[n][j] : NEG_INF;
                }
        }
        float mx[8];
#pragma unroll
        for (int n = 0; n < 8; ++n)
            mx[n] = fmaxf(fmaxf(fmaxf(sc[n][0], sc[n][1]), sc[n][2]), sc[n][3]);
        float pmax = fmaxf(
            fmaxf(fmaxf(mx[0], mx[1]), fmaxf(mx[2], mx[3])),
            fmaxf(fmaxf(mx[4], mx[5]), fmaxf(mx[6], mx[7])));

        if (__any(pmax > m_run + 8.f)) {
            float pm = fmaxf(pmax, __shfl_xor(pmax, 16));
            pm = fmaxf(pm, __shfl_xor(pm, 32));
            const float mnew = fmaxf(m_run, pm);
            const float alpha = exp2f(m_run - mnew);
            m_run = mnew;
            float al[4];
#pragma unroll
            for (int j = 0; j < 4; ++j) al[j] = __shfl(alpha, lg * 4 + j);
#pragma unroll
            for (int dn = 0; dn < 4; ++dn)
#pragma unroll
                for (int j = 0; j < 4; ++j) o[dn][j] *= al[j];
#pragma unroll
            for (int j = 0; j < 4; ++j) ol[j] *= al[j];
        }

#pragma unroll
        for (int n = 0; n < 8; ++n)
#pragma unroll
            for (int j = 0; j < 4; ++j) sc[n][j] = exp2f(sc[n][j] - m_run);

        // T12: P -> bf16 + permlane32_swap, two 64-k halves -> pa0..pa3
        union UW { unsigned w[4]; bf16x8 v; };
        bf16x8 pa0, pa1, pa2, pa3;
        {
            unsigned pk00, pk01, pk10, pk11, pk20, pk21, pk30, pk31;
            asm("v_cvt_pk_bf16_f32 %0, %1, %2" : "=v"(pk00) : "v"(sc[0][0]), "v"(sc[0][1]));
            asm("v_cvt_pk_bf16_f32 %0, %1, %2" : "=v"(pk01) : "v"(sc[0][2]), "v"(sc[0][3]));
            asm("v_cvt_pk_bf16_f32 %0, %1, %2" : "=v"(pk10) : "v"(sc[1][0]), "v"(sc[1][1]));
            asm("v_cvt_pk_bf16_f32 %0, %1, %2" : "=v"(pk11) : "v"(sc[1][2]), "v"(sc[1][3]));
            asm("v_cvt_pk_bf16_f32 %0, %1, %2" : "=v"(pk20) : "v"(sc[2][0]), "v"(sc[2][1]));
            asm("v_cvt_pk_bf16_f32 %0, %1, %2" : "=v"(pk21) : "v"(sc[2][2]), "v"(sc[2][3]));
            asm("v_cvt_pk_bf16_f32 %0, %1, %2" : "=v"(pk30) : "v"(sc[3][0]), "v"(sc[3][1]));
            asm("v_cvt_pk_bf16_f32 %0, %1, %2" : "=v"(pk31) : "v"(sc[3][2]), "v"(sc[3][3]));
            asm("v_permlane32_swap_b32 %0, %1" : "+v"(pk00), "+v"(pk10));
            asm("v_permlane32_swap_b32 %0, %1" : "+v"(pk01), "+v"(pk11));
            asm("v_permlane32_swap_b32 %0, %1" : "+v"(pk20), "+v"(pk30));
            asm("v_permlane32_swap_b32 %0, %1" : "+v"(pk21), "+v"(pk31));
            UW ua, ub;
            ua.w[0] = pk00; ua.w[1] = pk01; ua.w[2] = pk10; ua.w[3] = pk11;
            ub.w[0] = pk20; ub.w[1] = pk21; ub.w[2] = pk30; ub.w[3] = pk31;
            pa0 = ua.v; pa1 = ub.v;
        }
        {
            unsigned pk00, pk01, pk10, pk11, pk20, pk21, pk30, pk31;
            asm("v_cvt_pk_bf16_f32 %0, %1, %2" : "=v"(pk00) : "v"(sc[4][0]), "v"(sc[4][1]));
            asm("v_cvt_pk_bf16_f32 %0, %1, %2" : "=v"(pk01) : "v"(sc[4][2]), "v"(sc[4][3]));
            asm("v_cvt_pk_bf16_f32 %0, %1, %2" : "=v"(pk10) : "v"(sc[5][0]), "v"(sc[5][1]));
            asm("v_cvt_pk_bf16_f32 %0, %1, %2" : "=v"(pk11) : "v"(sc[5][2]), "v"(sc[5][3]));
            asm("v_cvt_pk_bf16_f32 %0, %1, %2" : "=v"(pk20) : "v"(sc[6][0]), "v"(sc[6][1]));
            asm("v_cvt_pk_bf16_f32 %0, %1, %2" : "=v"(pk21) : "v"(sc[6][2]), "v"(sc[6][3]));
            asm("v_cvt_pk_bf16_f32 %0, %1, %2" : "=v"(pk30) : "v"(sc[7][0]), "v"(sc[7][1]));
            asm("v_cvt_pk_bf16_f32 %0, %1, %2" : "=v"(pk31) : "v"(sc[7][2]), "v"(sc[7][3]));
            asm("v_permlane32_swap_b32 %0, %1" : "+v"(pk00), "+v"(pk10));
            asm("v_permlane32_swap_b32 %0, %1" : "+v"(pk01), "+v"(pk11));
            asm("v_permlane32_swap_b32 %0, %1" : "+v"(pk20), "+v"(pk30));
            asm("v_permlane32_swap_b32 %0, %1" : "+v"(pk21), "+v"(pk31));
            UW ua, ub;
            ua.w[0] = pk00; ua.w[1] = pk01; ua.w[2] = pk10; ua.w[3] = pk11;
            ub.w[0] = pk20; ub.w[1] = pk21; ub.w[2] = pk30; ub.w[3] = pk31;
            pa2 = ua.v; pa3 = ub.v;
        }

        // PV + ones-column: half-tile reads (128-B rows, same bases as K)
        __builtin_amdgcn_s_setprio(1);
#pragma unroll
        for (int dn = 0; dn < 4; ++dn) {
            bf16x8 vb0 = *(const bf16x8*)(Vc + (kfb0 + dn * 2048));
            bf16x8 vb1 = *(const bf16x8*)(Vc + (kfb1 + dn * 2048));
            bf16x8 vb2 = *(const bf16x8*)(Vc + (kfb0 + dn * 2048 + 8192));
            bf16x8 vb3 = *(const bf16x8*)(Vc + (kfb1 + dn * 2048 + 8192));
            o[dn] = __builtin_amdgcn_mfma_f32_16x16x32_bf16(pa0, vb0, o[dn], 0, 0, 0);
            o[dn] = __builtin_amdgcn_mfma_f32_16x16x32_bf16(pa1, vb1, o[dn], 0, 0, 0);
            o[dn] = __builtin_amdgcn_mfma_f32_16x16x32_bf16(pa2, vb2, o[dn], 0, 0, 0);
            o[dn] = __builtin_amdgcn_mfma_f32_16x16x32_bf16(pa3, vb3, o[dn], 0, 0, 0);
        }
        ol = __builtin_amdgcn_mfma_f32_16x16x32_bf16(pa0, ones, ol, 0, 0, 0);
        ol = __builtin_amdgcn_mfma_f32_16x16x32_bf16(pa1, ones, ol, 0, 0, 0);
        ol = __builtin_amdgcn_mfma_f32_16x16x32_bf16(pa2, ones, ol, 0, 0, 0);
        ol = __builtin_amdgcn_mfma_f32_16x16x32_bf16(pa3, ones, ol, 0, 0, 0);
        __builtin_amdgcn_s_setprio(0);

        if (more) {          // write-late
            stage(cur ^ 1, nk0, nk1, nv0, nv1);
        }
        __syncthreads();
        cur ^= 1;
    }

    float li[4];
#pragma unroll
    for (int j = 0; j < 4; ++j) li[j] = 1.0f / ol[j];
#pragma unroll
    for (int dn = 0; dn < 4; ++dn)
#pragma unroll
        for (int j = 0; j < 4; ++j) {
            const int row = b * SEQLEN + qb + lg * 4 + j;
            attn_out[(size_t)row * EMB + h * 64 + dn * 16 + lr] =
                (bf16_t)(o[dn][j] * li[j]);
        }
}

// ---------------------------------------------------------------------------
extern "C" void kernel_launch(void* const* d_in, const int* in_sizes, int n_in,
                              void* d_out, int out_size, void* d_ws, size_t ws_size,
                              hipStream_t stream)
{
    const float* X     = (const float*)d_in[0];
    const float* W_qkv = (const float*)d_in[1];
    const float* b_qkv = (const float*)d_in[2];
    const float* W_out = (const float*)d_in[3];
    const float* b_out = (const float*)d_in[4];
    float* out = (float*)d_out;

    char* ws = (char*)d_ws;
    bf16_t* Wqkv_t = (bf16_t*)ws;                           //  6 MB [3072][1024]
    bf16_t* Wout_t = (bf16_t*)(ws + 6u * 1024 * 1024);      //  2 MB [1024][1024]
    bf16_t* qkv    = (bf16_t*)(ws + 8u * 1024 * 1024);      // 24 MB [4096][3072] (V region unused)
    bf16_t* attn   = (bf16_t*)(ws + 32u * 1024 * 1024);     //  8 MB [4096][1024]
    bf16_t* Xb     = (bf16_t*)(ws + 40u * 1024 * 1024);     //  8 MB [4096][1024]
    bf16_t* Vt_g   = (bf16_t*)(ws + 48u * 1024 * 1024);     //  8 MB [32][64][2048] (quad-permuted)

    dim3 blk(256);
    prep_kernel<<<3072, blk, 0, stream>>>(X, W_qkv, W_out, Xb, Wqkv_t, Wout_t);

    // qkv = Xb @ W_qkv + b_qkv; V col-blocks written (quad-permuted) into Vt_g
    gemm_bt_kernel<true, true><<<(4096 / 128) * (N3 / 128), blk, 0, stream>>>(
        Xb, Wqkv_t, b_qkv, (void*)qkv, Vt_g, 1, 4096, N3, EMB);

    // causal flash attention (8-wave, QBLK=128, KVBLK=128) -> attn [4096][1024]
    attn_kernel<<<512, dim3(512), 0, stream>>>(qkv, Vt_g, attn);

    // out = attn @ W_out + b_out  (fp32 out)
    gemm_bt_kernel<false, false><<<(4096 / 128) * (EMB / 128), blk, 0, stream>>>(
        attn, Wout_t, b_out, (void*)out, nullptr, 0, 4096, EMB, EMB);
}

// Round 16
// 102.969 us; speedup vs baseline: 1.0834x; 1.0834x over previous
//
#include <hip/hip_runtime.h>

typedef __bf16 bf16_t;
typedef bf16_t bf16x8 __attribute__((ext_vector_type(8)));
typedef bf16_t bf16x4 __attribute__((ext_vector_type(4)));
typedef float f32x4 __attribute__((ext_vector_type(4)));

#define SEQLEN 2048
#define EMB 1024
#define NHEADS 16
#define N3 3072
#define NBATCH 2
#define NEG_INF (-__builtin_inff())
#define SC2 0.18033688011112042f   // 0.125 * log2(e): softmax in exp2 domain

// async global->LDS, 16B per lane. LDS base must be wave-uniform.
__device__ __forceinline__ void async16(bf16_t* lds, const bf16_t* g) {
    __builtin_amdgcn_global_load_lds(
        (const __attribute__((address_space(1))) void*)g,
        (__attribute__((address_space(3))) void*)lds, 16, 0, 0);
}

// ---------------------------------------------------------------------------
// prep: fused X fp32->bf16 convert (blocks 0..2047) + weight transpose/convert
// (blocks 2048..3071; W_qkv Q-cols pre-scaled by SC2).
// ---------------------------------------------------------------------------
__global__ __launch_bounds__(256) void prep_kernel(
    const float* __restrict__ X, const float* __restrict__ Wqkv,
    const float* __restrict__ Wout, bf16_t* __restrict__ Xb,
    bf16_t* __restrict__ Wqkv_t, bf16_t* __restrict__ Wout_t)
{
    __shared__ float tile[64][65];
    const int id = blockIdx.x;
    const int t = threadIdx.x;
    if (id < 2048) {
        const int i = (id * 256 + t) * 8;
        float4 a = *(const float4*)&X[i];
        float4 b = *(const float4*)&X[i + 4];
        bf16_t v[8];
        v[0] = (bf16_t)a.x; v[1] = (bf16_t)a.y; v[2] = (bf16_t)a.z; v[3] = (bf16_t)a.w;
        v[4] = (bf16_t)b.x; v[5] = (bf16_t)b.y; v[6] = (bf16_t)b.z; v[7] = (bf16_t)b.w;
        *(float4*)&Xb[i] = *(float4*)&v[0];
        return;
    }
    const int wid2 = id - 2048;
    int bx = wid2 & 63;
    const int k0 = (wid2 >> 6) << 6;
    const float* W; bf16_t* Wt; int N; float s;
    if (bx < 48) { W = Wqkv; Wt = Wqkv_t; N = N3;  s = (bx * 64 < EMB) ? SC2 : 1.0f; }
    else         { bx -= 48; W = Wout; Wt = Wout_t; N = EMB; s = 1.0f; }
    const int n0 = bx * 64;
    const int nl = t & 63, k4 = t >> 6;
#pragma unroll
    for (int i = 0; i < 16; ++i) {
        int kk = k4 + i * 4;
        tile[kk][nl] = W[(size_t)(k0 + kk) * N + n0 + nl];
    }
    __syncthreads();
    const int kl = t & 63, n4 = t >> 6;
#pragma unroll
    for (int i = 0; i < 16; ++i) {
        int nn = n4 + i * 4;
        Wt[(size_t)(n0 + nn) * EMB + k0 + kl] = (bf16_t)(tile[kl][nn] * s);
    }
}

// ---------------------------------------------------------------------------
// GEMM 128x128, BK=64, T2-swizzled, SINGLE-buffer (round-14 verified:
// 44 us GEMM1, MfmaUtil 22.7, 0 conflicts, 4+ blocks/CU). r15's explicit
// dbuf+vmcnt regressed (occupancy halved, FETCH doubled) - do not repeat.
// V_SPLIT epilogue stores V^T quad-permuted (sigma, r11-verified).
// ---------------------------------------------------------------------------
template<bool OUT_BF16, bool V_SPLIT>
__global__ __launch_bounds__(256) void gemm_bt_kernel(
    const bf16_t* __restrict__ A, const bf16_t* __restrict__ Bt,
    const float* __restrict__ bias, void* __restrict__ Cp,
    bf16_t* __restrict__ vt, int scale_q,
    int Mdim, int Ndim, int Kdim)
{
    __shared__ bf16_t As[128 * 64];   // 16 KB
    __shared__ bf16_t Bs[128 * 64];   // 16 KB
    const int nb = Ndim >> 7;
    const int cpx = gridDim.x >> 3;
    const int bid = (blockIdx.x & 7) * cpx + (blockIdx.x >> 3);
    const int bx = bid % nb, by = bid / nb;
    const int r0 = by << 7, c0 = bx << 7;
    const int t = threadIdx.x, lane = t & 63;
    const int wid = t >> 6;
    const int wm = wid >> 1, wn = wid & 1;
    const int lr = lane & 15, lg = lane >> 4;

    const int glrow = wid * 32 + (lane >> 3);
    const int gsw = ((lane & 7) ^ (lane >> 3)) << 3;     // elems
    const bf16_t* gA = &A[(size_t)(r0 + glrow) * Kdim + gsw];
    const bf16_t* gB = &Bt[(size_t)(c0 + glrow) * Kdim + gsw];
    bf16_t* ldsA = &As[wid * 2048];
    bf16_t* ldsB = &Bs[wid * 2048];
    const size_t row8 = (size_t)8 * Kdim;

    const int fragb0 = (lr * 128 + lg * 16) ^ ((lr & 7) << 4);
    const int fragb1 = (lr * 128 + 64 + lg * 16) ^ ((lr & 7) << 4);

    f32x4 acc[4][4] = {};
    const int KT = Kdim >> 6;
    for (int kt = 0; kt < KT; ++kt) {
        const bf16_t* a = gA + kt * 64;
        const bf16_t* b = gB + kt * 64;
        async16(ldsA,        a);
        async16(ldsA + 512,  a + row8);
        async16(ldsA + 1024, a + 2 * row8);
        async16(ldsA + 1536, a + 3 * row8);
        async16(ldsB,        b);
        async16(ldsB + 512,  b + row8);
        async16(ldsB + 1024, b + 2 * row8);
        async16(ldsB + 1536, b + 3 * row8);
        __syncthreads();

        const char* Ab = (const char*)As + wm * 8192;
        const char* Bb = (const char*)Bs + wn * 8192;
        bf16x8 af[4], bfm[4];
#pragma unroll
        for (int m = 0; m < 4; ++m)
            af[m] = *(const bf16x8*)(Ab + m * 2048 + fragb0);
#pragma unroll
        for (int n = 0; n < 4; ++n)
            bfm[n] = *(const bf16x8*)(Bb + n * 2048 + fragb0);
#pragma unroll
        for (int m = 0; m < 4; ++m)
#pragma unroll
            for (int n = 0; n < 4; ++n)
                acc[m][n] = __builtin_amdgcn_mfma_f32_16x16x32_bf16(
                    af[m], bfm[n], acc[m][n], 0, 0, 0);
#pragma unroll
        for (int m = 0; m < 4; ++m)
            af[m] = *(const bf16x8*)(Ab + m * 2048 + fragb1);
#pragma unroll
        for (int n = 0; n < 4; ++n)
            bfm[n] = *(const bf16x8*)(Bb + n * 2048 + fragb1);
#pragma unroll
        for (int m = 0; m < 4; ++m)
#pragma unroll
            for (int n = 0; n < 4; ++n)
                acc[m][n] = __builtin_amdgcn_mfma_f32_16x16x32_bf16(
                    af[m], bfm[n], acc[m][n], 0, 0, 0);
        __syncthreads();
    }

    const bool vmode = V_SPLIT && (c0 >= 2 * EMB);
    const int lgp = ((lg & 1) << 1) | (lg >> 1);   // sigma: 0->0,1->2,2->1,3->3
#pragma unroll
    for (int m = 0; m < 4; ++m) {
#pragma unroll
        for (int n = 0; n < 4; ++n) {
            const int col = c0 + wn * 64 + n * 16 + lr;
            float bval = bias[col];
            if (scale_q && col < EMB) bval *= SC2;
            if (vmode) {
                const int h = (col - 2 * EMB) >> 6, dd = col & 63;
                const int bb = r0 >> 11;
                const int sbase = (r0 & (SEQLEN - 1)) + wm * 64 + m * 16 + lgp * 4;
                bf16x4 pk;
#pragma unroll
                for (int j = 0; j < 4; ++j) pk[j] = (bf16_t)(acc[m][n][j] + bval);
                *(bf16x4*)&vt[(size_t)((bb * 16 + h) * 64 + dd) * SEQLEN + sbase] = pk;
            } else {
#pragma unroll
                for (int j = 0; j < 4; ++j) {
                    const int row = r0 + wm * 64 + m * 16 + lg * 4 + j;
                    const float v = acc[m][n][j] + bval;
                    if (OUT_BF16)
                        ((bf16_t*)Cp)[(size_t)row * Ndim + col] = (bf16_t)v;
                    else
                        ((float*)Cp)[(size_t)row * Ndim + col] = v;
                }
            }
        }
    }
}

// ---------------------------------------------------------------------------
// Causal flash attention v11 (r15-verified): 8-wave, QBLK=128, KVBLK=128,
// V^T as TWO [64 d][64 s] half-tiles (128-B rows, conflict-free 3-bit
// swizzle). Reg-staged issue-early/write-late, T12/T13, ones-column l.
// ---------------------------------------------------------------------------
__global__ __launch_bounds__(512, 4) void attn_kernel(
    const bf16_t* __restrict__ qkv, const bf16_t* __restrict__ vt,
    bf16_t* __restrict__ attn_out)
{
    __shared__ bf16_t Kl[2][8192];    // [128 k][64 d], 128-B rows
    __shared__ bf16_t Vl[2][8192];    // [2 s-half][64 d][64 s], 128-B rows
    const int d = blockIdx.x;
    const int r = d >> 8;
    const int u = (d >> 5) & 7;
    const int bh = d & 31;
    const int qt = r ? u : (15 - u);      // long blocks first
    const int b = bh >> 4, h = bh & 15;
    const int q0 = qt << 7;
    const int t = threadIdx.x, lane = t & 63, wid = t >> 6;
    const int lr = lane & 15, lg = lane >> 4;

    const int kfb0 = (lr * 128 + lg * 16) ^ ((lr & 7) << 4);
    const int kfb1 = (lr * 128 + 64 + lg * 16) ^ ((lr & 7) << 4);

    const int srk = t >> 3, sck = (t & 7) << 3;
    const int srv = t >> 4, scv = (t & 15) << 3;
    const int stbK = (srk * 128 + sck * 2) ^ ((srk & 7) << 4);
    const int stbV = (((srv * 128 + (scv & 63) * 2) ^ ((srv & 7) << 4)))
                     + ((scv >> 6) << 13);

    const bf16_t* kp = &qkv[(size_t)(b * SEQLEN + srk) * N3 + EMB + h * 64 + sck];
    const bf16_t* vp = &vt[(size_t)(bh * 64 + srv) * SEQLEN + scv];
    const size_t kstep  = (size_t)128 * N3;
    const size_t krow64 = (size_t)64 * N3;
    const size_t vrow32 = (size_t)32 * SEQLEN;

    const int qb = q0 + wid * 16;
    const int qg = qb + lr;
    bf16x8 qa0, qa1;
    {
        const bf16_t* qp = &qkv[(size_t)(b * SEQLEN + qg) * N3 + h * 64];
        qa0 = *(const bf16x8*)&qp[lg * 8];
        qa1 = *(const bf16x8*)&qp[32 + lg * 8];
    }
    bf16x8 ones;
#pragma unroll
    for (int i = 0; i < 8; ++i) ones[i] = (bf16_t)1.0f;

    f32x4 o[4] = {};
    f32x4 ol = {};
    float m_run = NEG_INF;

    auto stage = [&](int buf, float4 k0, float4 k1, float4 v0, float4 v1) {
        char* K = (char*)Kl[buf]; char* V = (char*)Vl[buf];
        *(float4*)(K + stbK) = k0; *(float4*)(K + stbK + 8192) = k1;
        *(float4*)(V + stbV) = v0; *(float4*)(V + stbV + 4096) = v1;
    };

    {   // prologue
        float4 k0 = *(const float4*)kp, k1 = *(const float4*)(kp + krow64);
        float4 v0 = *(const float4*)vp, v1 = *(const float4*)(vp + vrow32);
        stage(0, k0, k1, v0, v1);
    }
    __syncthreads();
    int cur = 0;
    for (int kt = 0; kt <= qt; ++kt) {
        float4 nk0, nk1, nv0, nv1;
        const bool more = (kt < qt);
        if (more) {          // T14 issue-early
            kp += kstep; vp += 128;
            nk0 = *(const float4*)kp; nk1 = *(const float4*)(kp + krow64);
            nv0 = *(const float4*)vp; nv1 = *(const float4*)(vp + vrow32);
        }

        const char* Kc = (const char*)Kl[cur];
        const char* Vc = (const char*)Vl[cur];
        const int kbase = kt << 7;

        f32x4 sc[8] = {};
        __builtin_amdgcn_s_setprio(1);
#pragma unroll
        for (int n = 0; n < 8; ++n) {
            bf16x8 kb0 = *(const bf16x8*)(Kc + (kfb0 + n * 2048));
            bf16x8 kb1 = *(const bf16x8*)(Kc + (kfb1 + n * 2048));
            sc[n] = __builtin_amdgcn_mfma_f32_16x16x32_bf16(kb0, qa0, sc[n], 0, 0, 0);
            sc[n] = __builtin_amdgcn_mfma_f32_16x16x32_bf16(kb1, qa1, sc[n], 0, 0, 0);
        }
        __builtin_amdgcn_s_setprio(0);

        if (kt == qt) {
#pragma unroll
            for (int n = 0; n < 8; ++n)
#pragma unroll
                for (int j = 0; j < 4; ++j) {
                    const int kg = kbase + n * 16 + lg * 4 + j;
                    sc[n][j] = (kg <= qg) ? sc[n][j] : NEG_INF;
                }
        }
        float mx[8];
#pragma unroll
        for (int n = 0; n < 8; ++n)
            mx[n] = fmaxf(fmaxf(fmaxf(sc[n][0], sc[n][1]), sc[n][2]), sc[n][3]);
        float pmax = fmaxf(
            fmaxf(fmaxf(mx[0], mx[1]), fmaxf(mx[2], mx[3])),
            fmaxf(fmaxf(mx[4], mx[5]), fmaxf(mx[6], mx[7])));

        if (__any(pmax > m_run + 8.f)) {
            float pm = fmaxf(pmax, __shfl_xor(pmax, 16));
            pm = fmaxf(pm, __shfl_xor(pm, 32));
            const float mnew = fmaxf(m_run, pm);
            const float alpha = exp2f(m_run - mnew);
            m_run = mnew;
            float al[4];
#pragma unroll
            for (int j = 0; j < 4; ++j) al[j] = __shfl(alpha, lg * 4 + j);
#pragma unroll
            for (int dn = 0; dn < 4; ++dn)
#pragma unroll
                for (int j = 0; j < 4; ++j) o[dn][j] *= al[j];
#pragma unroll
            for (int j = 0; j < 4; ++j) ol[j] *= al[j];
        }

#pragma unroll
        for (int n = 0; n < 8; ++n)
#pragma unroll
            for (int j = 0; j < 4; ++j) sc[n][j] = exp2f(sc[n][j] - m_run);

        // T12: P -> bf16 + permlane32_swap, two 64-k halves -> pa0..pa3
        union UW { unsigned w[4]; bf16x8 v; };
        bf16x8 pa0, pa1, pa2, pa3;
        {
            unsigned pk00, pk01, pk10, pk11, pk20, pk21, pk30, pk31;
            asm("v_cvt_pk_bf16_f32 %0, %1, %2" : "=v"(pk00) : "v"(sc[0][0]), "v"(sc[0][1]));
            asm("v_cvt_pk_bf16_f32 %0, %1, %2" : "=v"(pk01) : "v"(sc[0][2]), "v"(sc[0][3]));
            asm("v_cvt_pk_bf16_f32 %0, %1, %2" : "=v"(pk10) : "v"(sc[1][0]), "v"(sc[1][1]));
            asm("v_cvt_pk_bf16_f32 %0, %1, %2" : "=v"(pk11) : "v"(sc[1][2]), "v"(sc[1][3]));
            asm("v_cvt_pk_bf16_f32 %0, %1, %2" : "=v"(pk20) : "v"(sc[2][0]), "v"(sc[2][1]));
            asm("v_cvt_pk_bf16_f32 %0, %1, %2" : "=v"(pk21) : "v"(sc[2][2]), "v"(sc[2][3]));
            asm("v_cvt_pk_bf16_f32 %0, %1, %2" : "=v"(pk30) : "v"(sc[3][0]), "v"(sc[3][1]));
            asm("v_cvt_pk_bf16_f32 %0, %1, %2" : "=v"(pk31) : "v"(sc[3][2]), "v"(sc[3][3]));
            asm("v_permlane32_swap_b32 %0, %1" : "+v"(pk00), "+v"(pk10));
            asm("v_permlane32_swap_b32 %0, %1" : "+v"(pk01), "+v"(pk11));
            asm("v_permlane32_swap_b32 %0, %1" : "+v"(pk20), "+v"(pk30));
            asm("v_permlane32_swap_b32 %0, %1" : "+v"(pk21), "+v"(pk31));
            UW ua, ub;
            ua.w[0] = pk00; ua.w[1] = pk01; ua.w[2] = pk10; ua.w[3] = pk11;
            ub.w[0] = pk20; ub.w[1] = pk21; ub.w[2] = pk30; ub.w[3] = pk31;
            pa0 = ua.v; pa1 = ub.v;
        }
        {
            unsigned pk00, pk01, pk10, pk11, pk20, pk21, pk30, pk31;
            asm("v_cvt_pk_bf16_f32 %0, %1, %2" : "=v"(pk00) : "v"(sc[4][0]), "v"(sc[4][1]));
            asm("v_cvt_pk_bf16_f32 %0, %1, %2" : "=v"(pk01) : "v"(sc[4][2]), "v"(sc[4][3]));
            asm("v_cvt_pk_bf16_f32 %0, %1, %2" : "=v"(pk10) : "v"(sc[5][0]), "v"(sc[5][1]));
            asm("v_cvt_pk_bf16_f32 %0, %1, %2" : "=v"(pk11) : "v"(sc[5][2]), "v"(sc[5][3]));
            asm("v_cvt_pk_bf16_f32 %0, %1, %2" : "=v"(pk20) : "v"(sc[6][0]), "v"(sc[6][1]));
            asm("v_cvt_pk_bf16_f32 %0, %1, %2" : "=v"(pk21) : "v"(sc[6][2]), "v"(sc[6][3]));
            asm("v_cvt_pk_bf16_f32 %0, %1, %2" : "=v"(pk30) : "v"(sc[7][0]), "v"(sc[7][1]));
            asm("v_cvt_pk_bf16_f32 %0, %1, %2" : "=v"(pk31) : "v"(sc[7][2]), "v"(sc[7][3]));
            asm("v_permlane32_swap_b32 %0, %1" : "+v"(pk00), "+v"(pk10));
            asm("v_permlane32_swap_b32 %0, %1" : "+v"(pk01), "+v"(pk11));
            asm("v_permlane32_swap_b32 %0, %1" : "+v"(pk20), "+v"(pk30));
            asm("v_permlane32_swap_b32 %0, %1" : "+v"(pk21), "+v"(pk31));
            UW ua, ub;
            ua.w[0] = pk00; ua.w[1] = pk01; ua.w[2] = pk10; ua.w[3] = pk11;
            ub.w[0] = pk20; ub.w[1] = pk21; ub.w[2] = pk30; ub.w[3] = pk31;
            pa2 = ua.v; pa3 = ub.v;
        }

        // PV + ones-column: half-tile reads (128-B rows, same bases as K)
        __builtin_amdgcn_s_setprio(1);
#pragma unroll
        for (int dn = 0; dn < 4; ++dn) {
            bf16x8 vb0 = *(const bf16x8*)(Vc + (kfb0 + dn * 2048));
            bf16x8 vb1 = *(const bf16x8*)(Vc + (kfb1 + dn * 2048));
            bf16x8 vb2 = *(const bf16x8*)(Vc + (kfb0 + dn * 2048 + 8192));
            bf16x8 vb3 = *(const bf16x8*)(Vc + (kfb1 + dn * 2048 + 8192));
            o[dn] = __builtin_amdgcn_mfma_f32_16x16x32_bf16(pa0, vb0, o[dn], 0, 0, 0);
            o[dn] = __builtin_amdgcn_mfma_f32_16x16x32_bf16(pa1, vb1, o[dn], 0, 0, 0);
            o[dn] = __builtin_amdgcn_mfma_f32_16x16x32_bf16(pa2, vb2, o[dn], 0, 0, 0);
            o[dn] = __builtin_amdgcn_mfma_f32_16x16x32_bf16(pa3, vb3, o[dn], 0, 0, 0);
        }
        ol = __builtin_amdgcn_mfma_f32_16x16x32_bf16(pa0, ones, ol, 0, 0, 0);
        ol = __builtin_amdgcn_mfma_f32_16x16x32_bf16(pa1, ones, ol, 0, 0, 0);
        ol = __builtin_amdgcn_mfma_f32_16x16x32_bf16(pa2, ones, ol, 0, 0, 0);
        ol = __builtin_amdgcn_mfma_f32_16x16x32_bf16(pa3, ones, ol, 0, 0, 0);
        __builtin_amdgcn_s_setprio(0);

        if (more) {          // write-late
            stage(cur ^ 1, nk0, nk1, nv0, nv1);
        }
        __syncthreads();
        cur ^= 1;
    }

    float li[4];
#pragma unroll
    for (int j = 0; j < 4; ++j) li[j] = 1.0f / ol[j];
#pragma unroll
    for (int dn = 0; dn < 4; ++dn)
#pragma unroll
        for (int j = 0; j < 4; ++j) {
            const int row = b * SEQLEN + qb + lg * 4 + j;
            attn_out[(size_t)row * EMB + h * 64 + dn * 16 + lr] =
                (bf16_t)(o[dn][j] * li[j]);
        }
}

// ---------------------------------------------------------------------------
extern "C" void kernel_launch(void* const* d_in, const int* in_sizes, int n_in,
                              void* d_out, int out_size, void* d_ws, size_t ws_size,
                              hipStream_t stream)
{
    const float* X     = (const float*)d_in[0];
    const float* W_qkv = (const float*)d_in[1];
    const float* b_qkv = (const float*)d_in[2];
    const float* W_out = (const float*)d_in[3];
    const float* b_out = (const float*)d_in[4];
    float* out = (float*)d_out;

    char* ws = (char*)d_ws;
    bf16_t* Wqkv_t = (bf16_t*)ws;                           //  6 MB [3072][1024]
    bf16_t* Wout_t = (bf16_t*)(ws + 6u * 1024 * 1024);      //  2 MB [1024][1024]
    bf16_t* qkv    = (bf16_t*)(ws + 8u * 1024 * 1024);      // 24 MB [4096][3072] (V region unused)
    bf16_t* attn   = (bf16_t*)(ws + 32u * 1024 * 1024);     //  8 MB [4096][1024]
    bf16_t* Xb     = (bf16_t*)(ws + 40u * 1024 * 1024);     //  8 MB [4096][1024]
    bf16_t* Vt_g   = (bf16_t*)(ws + 48u * 1024 * 1024);     //  8 MB [32][64][2048] (quad-permuted)

    dim3 blk(256);
    prep_kernel<<<3072, blk, 0, stream>>>(X, W_qkv, W_out, Xb, Wqkv_t, Wout_t);

    // qkv = Xb @ W_qkv + b_qkv; V col-blocks written (quad-permuted) into Vt_g
    gemm_bt_kernel<true, true><<<(4096 / 128) * (N3 / 128), blk, 0, stream>>>(
        Xb, Wqkv_t, b_qkv, (void*)qkv, Vt_g, 1, 4096, N3, EMB);

    // causal flash attention (8-wave, QBLK=128, KVBLK=128) -> attn [4096][1024]
    attn_kernel<<<512, dim3(512), 0, stream>>>(qkv, Vt_g, attn);

    // out = attn @ W_out + b_out  (fp32 out)
    gemm_bt_kernel<false, false><<<(4096 / 128) * (EMB / 128), blk, 0, stream>>>(
        attn, Wout_t, b_out, (void*)out, nullptr, 0, 4096, EMB, EMB);
}